// Round 1
// baseline (923.626 us; speedup 1.0000x reference)
//
#include <hip/hip_runtime.h>
#include <hip/hip_bf16.h>

// Problem constants (Qwen3VLMoeTextExpertsTransposed): E=32,H=2048,I=768,K=4,T=2048
#define E_ 32
#define H_ 2048
#define I_ 768
#define K_ 4
#define T_ 2048
#define TWO_I 1536
#define MAXT 8   // max 128-row m-tiles per expert (1024 tokens; binomial mean 256, sigma ~16)

typedef __attribute__((ext_vector_type(8))) short short8;
typedef __attribute__((ext_vector_type(4))) float floatx4;

// ws layout (bytes)
#define WS_OFFSETS 0                 // int[33]
#define WS_IDS     1024              // int[8192] token id per slot (grouped by expert)
#define WS_WTS     (1024 + 32768)    // float[8192] routing weight per slot
#define WS_INTER   131072            // bf16[8192*768] silu(gate)*up

__device__ __forceinline__ unsigned short f2bf(float f) {
  union { float f; unsigned u; } v; v.f = f;
  unsigned r = v.u + 0x7FFFu + ((v.u >> 16) & 1u);   // RNE to bf16
  return (unsigned short)(r >> 16);
}

__device__ __forceinline__ short8 cvt8(float4 a, float4 b) {
  short8 r;
  r[0] = (short)f2bf(a.x); r[1] = (short)f2bf(a.y);
  r[2] = (short)f2bf(a.z); r[3] = (short)f2bf(a.w);
  r[4] = (short)f2bf(b.x); r[5] = (short)f2bf(b.y);
  r[6] = (short)f2bf(b.z); r[7] = (short)f2bf(b.w);
  return r;
}

// ---- Phase A: group (token, slot) pairs by expert, dedupe (numpy .set last-wins) ----
__global__ void build_routing(const int* __restrict__ idx, const float* __restrict__ w,
                              char* __restrict__ ws) {
  int* offs = (int*)(ws + WS_OFFSETS);
  int* ids  = (int*)(ws + WS_IDS);
  float* wt = (float*)(ws + WS_WTS);
  __shared__ int s_cnt[E_];
  __shared__ int s_pos[E_];
  int tid = threadIdx.x;
  if (tid < E_) s_cnt[tid] = 0;
  __syncthreads();
  for (int i = tid; i < T_ * K_; i += 256) {
    int t = i >> 2, j = i & 3;
    int e = idx[i];
    bool keep = true;   // keep only the LAST occurrence of a duplicated expert
    for (int j2 = j + 1; j2 < K_; ++j2) if (idx[t * K_ + j2] == e) keep = false;
    if (keep) atomicAdd(&s_cnt[e], 1);
  }
  __syncthreads();
  if (tid == 0) {
    int run = 0;
    for (int e = 0; e < E_; ++e) { offs[e] = run; s_pos[e] = run; run += s_cnt[e]; }
    offs[E_] = run;
  }
  __syncthreads();
  for (int i = tid; i < T_ * K_; i += 256) {
    int t = i >> 2, j = i & 3;
    int e = idx[i];
    bool keep = true;
    for (int j2 = j + 1; j2 < K_; ++j2) if (idx[t * K_ + j2] == e) keep = false;
    if (keep) {
      int p = atomicAdd(&s_pos[e], 1);
      ids[p] = t;
      wt[p] = w[i];
    }
  }
}

// ---- GEMM1: gathered hidden [cnt,2048] x gate_up[e][2048,1536], fused silu*up ----
// Block tile: 128 rows x 64 output cols (stages 64 gate + 64 up B-columns).
// 4 waves 2x2; wave tile 64x64-staged (2 gate ni-tiles + 2 up ni-tiles, same cols).
__global__ __launch_bounds__(256, 2) void gemm1(
    const float* __restrict__ hidden, const float* __restrict__ gup,
    char* __restrict__ ws) {
  const int* offs = (const int*)(ws + WS_OFFSETS);
  const int* ids  = (const int*)(ws + WS_IDS);
  unsigned short* inter = (unsigned short*)(ws + WS_INTER);

  int e = blockIdx.x, mt = blockIdx.y, nt = blockIdx.z;
  int start = offs[e];
  int cnt = offs[e + 1] - start;
  int m0 = mt * 128;
  if (m0 >= cnt) return;
  int mrem = cnt - m0;
  int n0 = nt * 64;

  // stride 40 shorts = 80B: keeps ds_*_b128 16B-aligned, spreads banks (gcd(20,32)=4)
  __shared__ __align__(16) unsigned short Al[128][40];
  __shared__ __align__(16) unsigned short Bl[128][40];

  int tid = threadIdx.x;
  int lane = tid & 63, wid = tid >> 6;
  int wy = wid >> 1, wx = wid & 1;
  int quad = lane >> 4, l15 = lane & 15;

  floatx4 acc[4][4];
#pragma unroll
  for (int a = 0; a < 4; ++a)
#pragma unroll
    for (int b = 0; b < 4; ++b) acc[a][b] = (floatx4){0.f, 0.f, 0.f, 0.f};

  // A staging map: 2 units/thread, each = 8 contiguous k of one row
  int am[2], ak[2], tok[2];
#pragma unroll
  for (int u = 0; u < 2; ++u) {
    int lin = tid + u * 256;
    am[u] = lin >> 2; ak[u] = (lin & 3) * 8;
    tok[u] = (am[u] < mrem) ? ids[start + m0 + am[u]] : -1;
  }
  // B staging map: col j (0..63 gate, 64..127 up), 16 k-rows per thread
  int bj = tid & 127;
  int bk0 = (tid >> 7) * 16;
  int gc = (bj < 64) ? (n0 + bj) : (I_ + n0 + (bj - 64));
  const float* gbase = gup + (size_t)e * H_ * TWO_I + gc;

  for (int kb = 0; kb < H_ / 32; ++kb) {
    // stage A (fp32 -> bf16), coalesced float4 loads, b128 LDS writes
#pragma unroll
    for (int u = 0; u < 2; ++u) {
      short8 av = (short8){0, 0, 0, 0, 0, 0, 0, 0};
      if (tok[u] >= 0) {
        const float* src = hidden + tok[u] * H_ + kb * 32 + ak[u];
        av = cvt8(*(const float4*)src, *(const float4*)(src + 4));
      }
      *(short8*)&Al[am[u]][ak[u]] = av;
    }
    // stage B transposed: lane-coalesced scalar column reads, packed b128 writes
    {
      const float* gk = gbase + (size_t)(kb * 32 + bk0) * TWO_I;
      unsigned short bv[16];
#pragma unroll
      for (int kr = 0; kr < 16; ++kr) bv[kr] = f2bf(gk[(size_t)kr * TWO_I]);
      short8 b0, b1;
#pragma unroll
      for (int q = 0; q < 8; ++q) { b0[q] = (short)bv[q]; b1[q] = (short)bv[8 + q]; }
      *(short8*)&Bl[bj][bk0] = b0;
      *(short8*)&Bl[bj][bk0 + 8] = b1;
    }
    __syncthreads();

    short8 af[4], bfr[4];
#pragma unroll
    for (int mi = 0; mi < 4; ++mi)
      af[mi] = *(const short8*)&Al[wy * 64 + mi * 16 + l15][quad * 8];
#pragma unroll
    for (int ni = 0; ni < 4; ++ni) {
      int j = (ni < 2) ? (wx * 32 + ni * 16 + l15) : (64 + wx * 32 + (ni - 2) * 16 + l15);
      bfr[ni] = *(const short8*)&Bl[j][quad * 8];
    }
#pragma unroll
    for (int mi = 0; mi < 4; ++mi)
#pragma unroll
      for (int ni = 0; ni < 4; ++ni)
        acc[mi][ni] = __builtin_amdgcn_mfma_f32_16x16x32_bf16(af[mi], bfr[ni], acc[mi][ni], 0, 0, 0);
    __syncthreads();
  }

  // epilogue: inter = silu(gate) * up, bf16 to ws
#pragma unroll
  for (int mi = 0; mi < 4; ++mi) {
#pragma unroll
    for (int r = 0; r < 4; ++r) {
      int row = wy * 64 + mi * 16 + quad * 4 + r;
      if (row < mrem) {
        int slot = start + m0 + row;
#pragma unroll
        for (int ni = 0; ni < 2; ++ni) {
          float g = acc[mi][ni][r];
          float u = acc[mi][ni + 2][r];
          float s = g / (1.f + __expf(-g));
          int col = n0 + wx * 32 + ni * 16 + l15;
          inter[(size_t)slot * I_ + col] = f2bf(s * u);
        }
      }
    }
  }
}

// ---- GEMM2: inter [cnt,768] x down[e][768,2048]; weighted atomicAdd into out ----
__global__ __launch_bounds__(256, 2) void gemm2(
    const float* __restrict__ down, float* __restrict__ out, char* __restrict__ ws) {
  const int* offs = (const int*)(ws + WS_OFFSETS);
  const int* ids  = (const int*)(ws + WS_IDS);
  const float* wt = (const float*)(ws + WS_WTS);
  const unsigned short* inter = (const unsigned short*)(ws + WS_INTER);

  int e = blockIdx.x, mt = blockIdx.y, nt = blockIdx.z;
  int start = offs[e];
  int cnt = offs[e + 1] - start;
  int m0 = mt * 128;
  if (m0 >= cnt) return;
  int mrem = cnt - m0;
  int n0 = nt * 128;

  __shared__ __align__(16) unsigned short Al[128][40];
  __shared__ __align__(16) unsigned short Bl[128][40];

  int tid = threadIdx.x;
  int lane = tid & 63, wid = tid >> 6;
  int wy = wid >> 1, wx = wid & 1;
  int quad = lane >> 4, l15 = lane & 15;

  floatx4 acc[4][4];
#pragma unroll
  for (int a = 0; a < 4; ++a)
#pragma unroll
    for (int b = 0; b < 4; ++b) acc[a][b] = (floatx4){0.f, 0.f, 0.f, 0.f};

  int am[2], ak[2];
#pragma unroll
  for (int u = 0; u < 2; ++u) {
    int lin = tid + u * 256;
    am[u] = lin >> 2; ak[u] = (lin & 3) * 8;
  }
  int bj = tid & 127;
  int bk0 = (tid >> 7) * 16;
  const float* dbase = down + (size_t)e * I_ * H_ + (n0 + bj);

  for (int kb = 0; kb < I_ / 32; ++kb) {
    // stage A: inter is already bf16 -> single 16B load + 16B LDS write
#pragma unroll
    for (int u = 0; u < 2; ++u) {
      uint4 av = (uint4){0u, 0u, 0u, 0u};
      if (am[u] < mrem)
        av = *(const uint4*)(inter + (size_t)(start + m0 + am[u]) * I_ + kb * 32 + ak[u]);
      *(uint4*)&Al[am[u]][ak[u]] = av;
    }
    // stage B transposed
    {
      const float* dk = dbase + (size_t)(kb * 32 + bk0) * H_;
      unsigned short bv[16];
#pragma unroll
      for (int kr = 0; kr < 16; ++kr) bv[kr] = f2bf(dk[(size_t)kr * H_]);
      short8 b0, b1;
#pragma unroll
      for (int q = 0; q < 8; ++q) { b0[q] = (short)bv[q]; b1[q] = (short)bv[8 + q]; }
      *(short8*)&Bl[bj][bk0] = b0;
      *(short8*)&Bl[bj][bk0 + 8] = b1;
    }
    __syncthreads();

    short8 af[4], bfr[4];
#pragma unroll
    for (int mi = 0; mi < 4; ++mi)
      af[mi] = *(const short8*)&Al[wy * 64 + mi * 16 + l15][quad * 8];
#pragma unroll
    for (int ni = 0; ni < 4; ++ni)
      bfr[ni] = *(const short8*)&Bl[wx * 64 + ni * 16 + l15][quad * 8];
#pragma unroll
    for (int mi = 0; mi < 4; ++mi)
#pragma unroll
      for (int ni = 0; ni < 4; ++ni)
        acc[mi][ni] = __builtin_amdgcn_mfma_f32_16x16x32_bf16(af[mi], bfr[ni], acc[mi][ni], 0, 0, 0);
    __syncthreads();
  }

  // epilogue: out[t, n] += w * val  (out zeroed by memset; K<=4 writers per address)
#pragma unroll
  for (int mi = 0; mi < 4; ++mi) {
#pragma unroll
    for (int r = 0; r < 4; ++r) {
      int row = wy * 64 + mi * 16 + quad * 4 + r;
      if (row < mrem) {
        int slot = start + m0 + row;
        int t = ids[slot];
        float w = wt[slot];
#pragma unroll
        for (int ni = 0; ni < 4; ++ni) {
          int col = n0 + wx * 64 + ni * 16 + l15;
          atomicAdd(out + (size_t)t * H_ + col, w * acc[mi][ni][r]);
        }
      }
    }
  }
}

extern "C" void kernel_launch(void* const* d_in, const int* in_sizes, int n_in,
                              void* d_out, int out_size, void* d_ws, size_t ws_size,
                              hipStream_t stream) {
  (void)in_sizes; (void)n_in; (void)out_size; (void)ws_size;
  const float* hidden = (const float*)d_in[0];
  const int* idx      = (const int*)d_in[1];
  const float* w      = (const float*)d_in[2];
  const float* gup    = (const float*)d_in[3];
  const float* down   = (const float*)d_in[4];
  float* out = (float*)d_out;
  char* ws = (char*)d_ws;

  hipMemsetAsync(d_out, 0, (size_t)T_ * H_ * sizeof(float), stream);
  build_routing<<<1, 256, 0, stream>>>(idx, w, ws);
  gemm1<<<dim3(E_, MAXT, I_ / 64), 256, 0, stream>>>(hidden, gup, ws);
  gemm2<<<dim3(E_, MAXT, H_ / 128), 256, 0, stream>>>(down, out, ws);
}

// Round 2
// 821.028 us; speedup vs baseline: 1.1250x; 1.1250x over previous
//
#include <hip/hip_runtime.h>
#include <hip/hip_bf16.h>

// Qwen3VLMoeTextExpertsTransposed: E=32,H=2048,I=768,K=4,T=2048
#define E_ 32
#define H_ 2048
#define I_ 768
#define T_ 2048
#define TWO_I 1536
#define MAX_TILES 96   // sum ceil(cnt/128) <= 32 + 8192/128 = 96

typedef __attribute__((ext_vector_type(8))) short short8;
typedef __attribute__((ext_vector_type(4))) float floatx4;

// ws layout (bytes)
#define WS_OFFSETS 0                       // int[33]
#define WS_IDS     1024                    // int[8192]
#define WS_WTS     (1024 + 32768)          // float[8192]
#define WS_TILES   (1024 + 65536)          // int[96]: (e<<16)|mtile, -1 = dead
#define WS_INTER   131072                  // bf16[8192*768]
#define WS_HID16   (131072 + 8192*768*2)   // bf16[2048*2048]

__device__ __forceinline__ unsigned short f2bf(float f) {
  union { float f; unsigned u; } v; v.f = f;
  unsigned r = v.u + 0x7FFFu + ((v.u >> 16) & 1u);   // RNE
  return (unsigned short)(r >> 16);
}

__device__ __forceinline__ unsigned pkbf(float a, float b) {
  // packed fp32->bf16 RNE pair; lowers to v_cvt_pk_bf16_f32 when available
  __hip_bfloat162 h = __float22bfloat162_rn(float2{a, b});
  union { __hip_bfloat162 h; unsigned u; } v; v.h = h; return v.u;
}

// ---- routing: group slots by expert (dedupe = numpy last-write-wins) + tile list ----
__global__ void build_routing(const int* __restrict__ idx, const float* __restrict__ w,
                              char* __restrict__ ws) {
  int* offs = (int*)(ws + WS_OFFSETS);
  int* ids  = (int*)(ws + WS_IDS);
  float* wt = (float*)(ws + WS_WTS);
  int* tiles = (int*)(ws + WS_TILES);
  __shared__ int s_cnt[E_];
  __shared__ int s_pos[E_];
  int tid = threadIdx.x;
  if (tid < E_) s_cnt[tid] = 0;
  __syncthreads();
  for (int i = tid; i < T_ * 4; i += 256) {
    int t = i >> 2, j = i & 3;
    int e = idx[i];
    bool keep = true;
    for (int j2 = j + 1; j2 < 4; ++j2) if (idx[t * 4 + j2] == e) keep = false;
    if (keep) atomicAdd(&s_cnt[e], 1);
  }
  __syncthreads();
  if (tid == 0) {
    int run = 0;
    for (int e = 0; e < E_; ++e) { offs[e] = run; s_pos[e] = run; run += s_cnt[e]; }
    offs[E_] = run;
    int nt = 0;
    for (int e = 0; e < E_; ++e)
      for (int m0 = 0; m0 < s_cnt[e]; m0 += 128) tiles[nt++] = (e << 16) | (m0 >> 7);
    for (; nt < MAX_TILES; ++nt) tiles[nt] = -1;
  }
  __syncthreads();
  for (int i = tid; i < T_ * 4; i += 256) {
    int t = i >> 2, j = i & 3;
    int e = idx[i];
    bool keep = true;
    for (int j2 = j + 1; j2 < 4; ++j2) if (idx[t * 4 + j2] == e) keep = false;
    if (keep) {
      int p = atomicAdd(&s_pos[e], 1);
      ids[p] = t;
      wt[p] = w[i];
    }
  }
}

// ---- hidden fp32 -> bf16 once (removes per-tile cvt from gemm1 hot loop) ----
__global__ void cvt_hidden(const float* __restrict__ hs, char* __restrict__ ws) {
  int g = blockIdx.x * 256 + threadIdx.x;            // 524288 threads, 8 elem each
  const float4 f0 = ((const float4*)hs)[g * 2];
  const float4 f1 = ((const float4*)hs)[g * 2 + 1];
  uint4 o;
  o.x = pkbf(f0.x, f0.y); o.y = pkbf(f0.z, f0.w);
  o.z = pkbf(f1.x, f1.y); o.w = pkbf(f1.z, f1.w);
  ((uint4*)(ws + WS_HID16))[g] = o;
}

// ---- GEMM1: gathered hid16 [cnt,2048] x gate_up[e][2048,1536], fused silu*up ----
// BM=128, BK=64, B-rows = 64 gate + 64 up. Register prefetch across barrier.
__global__ __launch_bounds__(256, 2) void gemm1(
    const float* __restrict__ gup, char* __restrict__ ws) {
  const int* offs = (const int*)(ws + WS_OFFSETS);
  const int* ids  = (const int*)(ws + WS_IDS);
  const int* tiles = (const int*)(ws + WS_TILES);
  const unsigned short* h16 = (const unsigned short*)(ws + WS_HID16);
  unsigned short* inter = (unsigned short*)(ws + WS_INTER);

  int tl = tiles[blockIdx.y];
  if (tl < 0) return;
  int e = tl >> 16, m0 = (tl & 0xffff) << 7;
  int start = offs[e];
  int mrem = offs[e + 1] - start - m0;
  int n0 = blockIdx.x * 64;

  __shared__ __align__(16) unsigned short Al[128][72];  // pitch 72 shorts: 16B-aligned rows
  __shared__ __align__(16) unsigned short Bl[128][72];

  int tid = threadIdx.x, lane = tid & 63, wid = tid >> 6;
  int wy = wid >> 1, wx = wid & 1, quad = lane >> 4, l15 = lane & 15;

  floatx4 acc[4][4] = {};

  // A map: 4 units/thread, unit = 8 contiguous k of one row
  int arow[4], ako[4];
  const unsigned short* asrc[4];
#pragma unroll
  for (int u = 0; u < 4; ++u) {
    int lin = tid + u * 256;
    arow[u] = lin >> 3; ako[u] = (lin & 7) * 8;
    int tok = (arow[u] < mrem) ? ids[start + m0 + arow[u]] : -1;
    asrc[u] = (tok >= 0) ? h16 + (size_t)tok * H_ + ako[u] : nullptr;
  }
  // B map: col bj (0..63 gate, 64..127 up), 32 k-rows/thread (lane-coalesced rows)
  int bj = tid & 127;
  int kr0 = (tid >> 7) * 32;
  int gc = (bj < 64) ? (n0 + bj) : (I_ + n0 + (bj - 64));
  const float* gbase = gup + (size_t)e * H_ * TWO_I + gc;

  uint4 pf_a[4];
  float pf_b[32];

  auto loadA = [&](int kb) {
#pragma unroll
    for (int u = 0; u < 4; ++u)
      pf_a[u] = asrc[u] ? *(const uint4*)(asrc[u] + (size_t)kb * 64) : uint4{0u, 0u, 0u, 0u};
  };
  auto loadB = [&](int kb) {
    const float* p = gbase + (size_t)(kb * 64 + kr0) * TWO_I;
#pragma unroll
    for (int r = 0; r < 32; ++r) pf_b[r] = p[(size_t)r * TWO_I];
  };

  loadA(0); loadB(0);
  for (int kb = 0; kb < H_ / 64; ++kb) {
    // regs -> LDS (A already bf16; B cvt packed)
#pragma unroll
    for (int u = 0; u < 4; ++u) *(uint4*)&Al[arow[u]][ako[u]] = pf_a[u];
#pragma unroll
    for (int q = 0; q < 4; ++q) {
      uint4 wv;
      wv.x = pkbf(pf_b[q * 8 + 0], pf_b[q * 8 + 1]);
      wv.y = pkbf(pf_b[q * 8 + 2], pf_b[q * 8 + 3]);
      wv.z = pkbf(pf_b[q * 8 + 4], pf_b[q * 8 + 5]);
      wv.w = pkbf(pf_b[q * 8 + 6], pf_b[q * 8 + 7]);
      *(uint4*)&Bl[bj][kr0 + q * 8] = wv;
    }
    __syncthreads();
    if (kb + 1 < H_ / 64) { loadA(kb + 1); loadB(kb + 1); }  // prefetch under compute
#pragma unroll
    for (int ks = 0; ks < 2; ++ks) {
      short8 af[4], bfr[4];
#pragma unroll
      for (int mi = 0; mi < 4; ++mi)
        af[mi] = *(const short8*)&Al[wy * 64 + mi * 16 + l15][ks * 32 + quad * 8];
#pragma unroll
      for (int ni = 0; ni < 4; ++ni) {
        int j = (ni < 2) ? (wx * 32 + ni * 16 + l15) : (64 + wx * 32 + (ni - 2) * 16 + l15);
        bfr[ni] = *(const short8*)&Bl[j][ks * 32 + quad * 8];
      }
#pragma unroll
      for (int mi = 0; mi < 4; ++mi)
#pragma unroll
        for (int ni = 0; ni < 4; ++ni)
          acc[mi][ni] = __builtin_amdgcn_mfma_f32_16x16x32_bf16(af[mi], bfr[ni], acc[mi][ni], 0, 0, 0);
    }
    __syncthreads();
  }

  // epilogue: inter = silu(gate) * up
#pragma unroll
  for (int mi = 0; mi < 4; ++mi) {
#pragma unroll
    for (int r = 0; r < 4; ++r) {
      int row = wy * 64 + mi * 16 + quad * 4 + r;
      if (row < mrem) {
        int slot = start + m0 + row;
#pragma unroll
        for (int ni = 0; ni < 2; ++ni) {
          float g = acc[mi][ni][r];
          float u = acc[mi][ni + 2][r];
          float s = g / (1.f + __expf(-g));
          int col = n0 + wx * 32 + ni * 16 + l15;
          inter[(size_t)slot * I_ + col] = f2bf(s * u);
        }
      }
    }
  }
}

// ---- GEMM2: inter [cnt,768] x down[e][768,2048]; weighted atomicAdd ----
__global__ __launch_bounds__(256, 2) void gemm2(
    const float* __restrict__ down, float* __restrict__ out, char* __restrict__ ws) {
  const int* offs = (const int*)(ws + WS_OFFSETS);
  const int* ids  = (const int*)(ws + WS_IDS);
  const float* wt = (const float*)(ws + WS_WTS);
  const int* tiles = (const int*)(ws + WS_TILES);
  const unsigned short* inter = (const unsigned short*)(ws + WS_INTER);

  int tl = tiles[blockIdx.y];
  if (tl < 0) return;
  int e = tl >> 16, m0 = (tl & 0xffff) << 7;
  int start = offs[e];
  int mrem = offs[e + 1] - start - m0;
  int n0 = blockIdx.x * 128;

  __shared__ __align__(16) unsigned short Al[128][72];
  __shared__ __align__(16) unsigned short Bl[128][72];

  int tid = threadIdx.x, lane = tid & 63, wid = tid >> 6;
  int wy = wid >> 1, wx = wid & 1, quad = lane >> 4, l15 = lane & 15;

  floatx4 acc[4][4] = {};

  int arow[4], ako[4];
  const unsigned short* asrc[4];
#pragma unroll
  for (int u = 0; u < 4; ++u) {
    int lin = tid + u * 256;
    arow[u] = lin >> 3; ako[u] = (lin & 7) * 8;
    asrc[u] = (arow[u] < mrem) ? inter + (size_t)(start + m0 + arow[u]) * I_ + ako[u] : nullptr;
  }
  int bj = tid & 127;
  int kr0 = (tid >> 7) * 32;
  const float* dbase = down + (size_t)e * I_ * H_ + (n0 + bj);

  uint4 pf_a[4];
  float pf_b[32];

  auto loadA = [&](int kb) {
#pragma unroll
    for (int u = 0; u < 4; ++u)
      pf_a[u] = asrc[u] ? *(const uint4*)(asrc[u] + (size_t)kb * 64) : uint4{0u, 0u, 0u, 0u};
  };
  auto loadB = [&](int kb) {
    const float* p = dbase + (size_t)(kb * 64 + kr0) * H_;
#pragma unroll
    for (int r = 0; r < 32; ++r) pf_b[r] = p[(size_t)r * H_];
  };

  loadA(0); loadB(0);
  for (int kb = 0; kb < I_ / 64; ++kb) {
#pragma unroll
    for (int u = 0; u < 4; ++u) *(uint4*)&Al[arow[u]][ako[u]] = pf_a[u];
#pragma unroll
    for (int q = 0; q < 4; ++q) {
      uint4 wv;
      wv.x = pkbf(pf_b[q * 8 + 0], pf_b[q * 8 + 1]);
      wv.y = pkbf(pf_b[q * 8 + 2], pf_b[q * 8 + 3]);
      wv.z = pkbf(pf_b[q * 8 + 4], pf_b[q * 8 + 5]);
      wv.w = pkbf(pf_b[q * 8 + 6], pf_b[q * 8 + 7]);
      *(uint4*)&Bl[bj][kr0 + q * 8] = wv;
    }
    __syncthreads();
    if (kb + 1 < I_ / 64) { loadA(kb + 1); loadB(kb + 1); }
#pragma unroll
    for (int ks = 0; ks < 2; ++ks) {
      short8 af[4], bfr[4];
#pragma unroll
      for (int mi = 0; mi < 4; ++mi)
        af[mi] = *(const short8*)&Al[wy * 64 + mi * 16 + l15][ks * 32 + quad * 8];
#pragma unroll
      for (int ni = 0; ni < 4; ++ni)
        bfr[ni] = *(const short8*)&Bl[wx * 64 + ni * 16 + l15][ks * 32 + quad * 8];
#pragma unroll
      for (int mi = 0; mi < 4; ++mi)
#pragma unroll
        for (int ni = 0; ni < 4; ++ni)
          acc[mi][ni] = __builtin_amdgcn_mfma_f32_16x16x32_bf16(af[mi], bfr[ni], acc[mi][ni], 0, 0, 0);
    }
    __syncthreads();
  }

#pragma unroll
  for (int mi = 0; mi < 4; ++mi) {
#pragma unroll
    for (int r = 0; r < 4; ++r) {
      int row = wy * 64 + mi * 16 + quad * 4 + r;
      if (row < mrem) {
        int slot = start + m0 + row;
        int t = ids[slot];
        float w = wt[slot];
#pragma unroll
        for (int ni = 0; ni < 4; ++ni) {
          int col = n0 + wx * 64 + ni * 16 + l15;
          atomicAdd(out + (size_t)t * H_ + col, w * acc[mi][ni][r]);
        }
      }
    }
  }
}

extern "C" void kernel_launch(void* const* d_in, const int* in_sizes, int n_in,
                              void* d_out, int out_size, void* d_ws, size_t ws_size,
                              hipStream_t stream) {
  (void)in_sizes; (void)n_in; (void)out_size; (void)ws_size;
  const float* hidden = (const float*)d_in[0];
  const int* idx      = (const int*)d_in[1];
  const float* w      = (const float*)d_in[2];
  const float* gup    = (const float*)d_in[3];
  const float* down   = (const float*)d_in[4];
  float* out = (float*)d_out;
  char* ws = (char*)d_ws;

  hipMemsetAsync(d_out, 0, (size_t)T_ * H_ * sizeof(float), stream);
  build_routing<<<1, 256, 0, stream>>>(idx, w, ws);
  cvt_hidden<<<T_ * H_ / 8 / 256, 256, 0, stream>>>(hidden, ws);
  gemm1<<<dim3(I_ / 64, MAX_TILES), 256, 0, stream>>>(gup, ws);
  gemm2<<<dim3(H_ / 128, MAX_TILES), 256, 0, stream>>>(down, out, ws);
}